// Round 4
// baseline (109.768 us; speedup 1.0000x reference)
//
#include <hip/hip_runtime.h>

#define NTOK 4096

typedef __attribute__((ext_vector_type(8))) short short8;
typedef __attribute__((ext_vector_type(4))) float f32x4;
typedef __attribute__((ext_vector_type(4))) unsigned int uint4v;

__device__ __forceinline__ unsigned short f2bf(float f) {
    unsigned u = __float_as_uint(f);
    u += 0x7fffu + ((u >> 16) & 1u);   // RNE; inputs finite
    return (unsigned short)(u >> 16);
}

__device__ __forceinline__ float bf2f(unsigned short h) {
    return __uint_as_float((unsigned)h << 16);
}

// pack two fp32 -> bf16 pair (truncation) in one v_perm_b32
__device__ __forceinline__ unsigned int pk2(float lo, float hi) {
    return __builtin_amdgcn_perm(__float_as_uint(hi), __float_as_uint(lo), 0x07060302u);
}

// ---------------- projection ----------------
// grid (64 n-tiles, 2 b, 5 ogrp): ogrp0 = q(8)+k(8), ogrp1..4 = v channels 16 each
// outputs: qbf/kbf [b][n][8] bf16 (q pre-scaled by log2e),
// vtp TILE-CONTIGUOUS: per (32-m group T, ct) a 1 KB block in exact lane order:
//   short index = ((T*4 + ct)*64 + lane)*8 + j, lane = (ch&15) + 16*quad,
//   (quad, j) from the verified p-permutation p = quad*8+j of m within group.
// One attention A-fragment load = 64 lanes x 16 B = 1 KB contiguous burst.
__global__ __launch_bounds__(256) void proj(
    const float* __restrict__ x, const float* __restrict__ ctx,
    const float* __restrict__ Wq, const float* __restrict__ bq,
    const float* __restrict__ Wk, const float* __restrict__ bk,
    const float* __restrict__ Wv, const float* __restrict__ bv,
    unsigned short* __restrict__ qbf, unsigned short* __restrict__ kbf,
    unsigned short* __restrict__ vtp)
{
    __shared__ float sW[16 * 64];
    __shared__ float sB[16];
    int tid  = threadIdx.x;
    int ogrp = blockIdx.z;
    int b    = blockIdx.y;
    int n0   = blockIdx.x * 64;

    if (ogrp == 0) {
        for (int i = tid; i < 1024; i += 256)
            sW[i] = (i < 512) ? Wq[i] : Wk[i - 512];
        if (tid < 16) sB[tid] = (tid < 8) ? bq[tid] : bk[tid - 8];
    } else {
        for (int i = tid; i < 1024; i += 256)
            sW[i] = Wv[(ogrp - 1) * 1024 + i];
        if (tid < 16) sB[tid] = bv[(ogrp - 1) * 16 + tid];
    }
    __syncthreads();

    int nn   = tid & 63;
    int osub = tid >> 6;
    const float* inp = (ogrp == 0 && osub < 2) ? x : ctx;
    const float* ip  = inp + (size_t)b * 64 * NTOK + n0 + nn;

    float a0 = sB[osub * 4 + 0], a1 = sB[osub * 4 + 1];
    float a2 = sB[osub * 4 + 2], a3 = sB[osub * 4 + 3];
#pragma unroll 16
    for (int c = 0; c < 64; ++c) {
        float val = ip[(size_t)c * NTOK];
        a0 += sW[(osub * 4 + 0) * 64 + c] * val;
        a1 += sW[(osub * 4 + 1) * 64 + c] * val;
        a2 += sW[(osub * 4 + 2) * 64 + c] * val;
        a3 += sW[(osub * 4 + 3) * 64 + c] * val;
    }
    float av[4] = {a0, a1, a2, a3};

    if (ogrp == 0) {
        bool isq = osub < 2;
        float sc = isq ? 1.4426950408889634f : 1.0f;   // fold log2e into q
        unsigned short* dst = isq ? qbf : kbf;
        int half = osub & 1;
        ushort4 pk = {f2bf(av[0] * sc), f2bf(av[1] * sc), f2bf(av[2] * sc), f2bf(av[3] * sc)};
        *(ushort4*)&dst[((size_t)b * NTOK + n0 + nn) * 8 + half * 4] = pk;
    } else {                          // vtp bf16, tile-contiguous layout
        int cbase = (ogrp - 1) * 16 + osub * 4;
        int m   = n0 + nn;
        int T   = m >> 5;
        int mm  = m & 31;
        int p   = ((mm >> 2) & 3) * 8 + (mm >> 4) * 4 + (mm & 3);  // verified perm
        int qd  = p >> 3, j2 = p & 7;
        int ctv = cbase >> 4;          // constant across the 4 channels
        unsigned short* vB = vtp + (size_t)b * 64 * NTOK
                           + ((size_t)T * 4 + ctv) * 512;
#pragma unroll
        for (int jj = 0; jj < 4; ++jj) {
            int lanev = ((cbase + jj) & 15) + 16 * qd;
            vB[lanev * 8 + j2] = f2bf(av[jj]);
        }
    }
}

// ---------------- fused flash attention: wave-per-n-group, barrier-free -----
// block: (64-row n-tile nt, b, m-eighth qz), 256 thr = 4 waves, qz=8: 1024
// blocks = 4 blocks/CU = 16 waves/CU (single residency pass).
// NEW (R4): waves split the N axis, not M. Wave w owns rows n0+w*16..+16 and
// iterates ALL 512 m of the qz slice (8 halves of 64). Per-wave MFMA/exp/pack
// totals identical to the m-split version (8 halves x 1 g == 2 halves x 4 g),
// but each wave's acc[4] is a COMPLETE 16n x 64c partial:
//   - cross-wave LDS reduce (64 ds_write + 64 ds_read /thread) GONE
//   - all 8 __syncthreads GONE; attn8 uses zero LDS
//   - acc VGPRs 64 -> 16; launch_bounds(256,4) pins 4 blocks/CU
// Cost: K/V fragment loads x4 per wave (all waves read the same m-range), but
// vtp+kbf are L2-resident (~1 MB/b) so only issue slots, hidden by 16 waves/CU.
// Per-half machinery verbatim from verified attn5/6/7: S via mfma_16x16x32_bf16
// (K slots 8..31 zero, exec-masked quad-0 loads); S D-regs feed PV B-frags
// under the p-permutation; native v_exp2 (q carries log2e); no max-subtraction
// (energies bounded). Channel mapping c = ct*16 + quad*4 + r, n = w*16 + n —
// identical bytes in partO/partL as the old sOc path (g -> w), mergeq untouched.
__global__ __launch_bounds__(256, 4) void attn8(
    const unsigned short* __restrict__ qbf, const unsigned short* __restrict__ kbf,
    const unsigned short* __restrict__ vtp,
    unsigned short* __restrict__ partO, float* __restrict__ partL)
{
    int tid  = threadIdx.x;
    int w    = tid >> 6, lane = tid & 63;
    int n    = lane & 15, quad = lane >> 4;
    int nt   = blockIdx.x;
    int b    = blockIdx.y;
    int qz   = blockIdx.z;           // 0..7
    int n0   = nt * 64;

    const f32x4 z4 = {0.f, 0.f, 0.f, 0.f};
    const short8 z8 = {0, 0, 0, 0, 0, 0, 0, 0};

    // single Q fragment: wave w's 16 rows
    short8 bqf = (quad == 0)
        ? *(const short8*)&qbf[((size_t)b * NTOK + n0 + w * 16 + n) * 8]
        : z8;

    const unsigned short* kb = kbf + (size_t)b * NTOK * 8;
    const unsigned short* vb = vtp + (size_t)b * 64 * NTOK;
    int mqbase = qz * 512;

    f32x4 acc[4] = {z4, z4, z4, z4};
    float lsum = 0.f;

    for (int h = 0; h < 8; ++h) {
        int m0 = mqbase + h * 64;
        int Tb = m0 >> 5;             // two 32-m groups: Tb, Tb+1

        short8 kf0 = (quad == 0) ? *(const short8*)&kb[(size_t)(m0 + 0 * 16 + n) * 8] : z8;
        short8 kf1 = (quad == 0) ? *(const short8*)&kb[(size_t)(m0 + 1 * 16 + n) * 8] : z8;
        short8 kf2 = (quad == 0) ? *(const short8*)&kb[(size_t)(m0 + 2 * 16 + n) * 8] : z8;
        short8 kf3 = (quad == 0) ? *(const short8*)&kb[(size_t)(m0 + 3 * 16 + n) * 8] : z8;

        // V fragments: 1 KB contiguous per load (lane-indexed tile)
        short8 af[2][4];
#pragma unroll
        for (int s = 0; s < 2; ++s)
#pragma unroll
            for (int ct = 0; ct < 4; ++ct)
                af[s][ct] = *(const short8*)&vb[(((size_t)(Tb + s) * 4 + ct) * 64 + lane) * 8];

        f32x4 sa0 = __builtin_amdgcn_mfma_f32_16x16x32_bf16(kf0, bqf, z4, 0, 0, 0);
        f32x4 sa1 = __builtin_amdgcn_mfma_f32_16x16x32_bf16(kf1, bqf, z4, 0, 0, 0);
        f32x4 sa2 = __builtin_amdgcn_mfma_f32_16x16x32_bf16(kf2, bqf, z4, 0, 0, 0);
        f32x4 sa3 = __builtin_amdgcn_mfma_f32_16x16x32_bf16(kf3, bqf, z4, 0, 0, 0);

        float e00 = __builtin_amdgcn_exp2f(sa0[0]), e01 = __builtin_amdgcn_exp2f(sa0[1]);
        float e02 = __builtin_amdgcn_exp2f(sa0[2]), e03 = __builtin_amdgcn_exp2f(sa0[3]);
        float e10 = __builtin_amdgcn_exp2f(sa1[0]), e11 = __builtin_amdgcn_exp2f(sa1[1]);
        float e12 = __builtin_amdgcn_exp2f(sa1[2]), e13 = __builtin_amdgcn_exp2f(sa1[3]);
        float e20 = __builtin_amdgcn_exp2f(sa2[0]), e21 = __builtin_amdgcn_exp2f(sa2[1]);
        float e22 = __builtin_amdgcn_exp2f(sa2[2]), e23 = __builtin_amdgcn_exp2f(sa2[3]);
        float e30 = __builtin_amdgcn_exp2f(sa3[0]), e31 = __builtin_amdgcn_exp2f(sa3[1]);
        float e32 = __builtin_amdgcn_exp2f(sa3[2]), e33 = __builtin_amdgcn_exp2f(sa3[3]);
        lsum += ((e00 + e01) + (e02 + e03)) + ((e10 + e11) + (e12 + e13))
              + ((e20 + e21) + (e22 + e23)) + ((e30 + e31) + (e32 + e33));

        uint4v t0, t1;
        t0[0] = pk2(e00, e01); t0[1] = pk2(e02, e03);
        t0[2] = pk2(e10, e11); t0[3] = pk2(e12, e13);
        t1[0] = pk2(e20, e21); t1[1] = pk2(e22, e23);
        t1[2] = pk2(e30, e31); t1[3] = pk2(e32, e33);
        short8 pf0 = __builtin_bit_cast(short8, t0);
        short8 pf1 = __builtin_bit_cast(short8, t1);

        acc[0] = __builtin_amdgcn_mfma_f32_16x16x32_bf16(af[0][0], pf0, acc[0], 0, 0, 0);
        acc[1] = __builtin_amdgcn_mfma_f32_16x16x32_bf16(af[0][1], pf0, acc[1], 0, 0, 0);
        acc[2] = __builtin_amdgcn_mfma_f32_16x16x32_bf16(af[0][2], pf0, acc[2], 0, 0, 0);
        acc[3] = __builtin_amdgcn_mfma_f32_16x16x32_bf16(af[0][3], pf0, acc[3], 0, 0, 0);
        acc[0] = __builtin_amdgcn_mfma_f32_16x16x32_bf16(af[1][0], pf1, acc[0], 0, 0, 0);
        acc[1] = __builtin_amdgcn_mfma_f32_16x16x32_bf16(af[1][1], pf1, acc[1], 0, 0, 0);
        acc[2] = __builtin_amdgcn_mfma_f32_16x16x32_bf16(af[1][2], pf1, acc[2], 0, 0, 0);
        acc[3] = __builtin_amdgcn_mfma_f32_16x16x32_bf16(af[1][3], pf1, acc[3], 0, 0, 0);
    }

    // ---- epilogue: barrier-free, no LDS
    float l = lsum;
    l += __shfl_xor(l, 16);
    l += __shfl_xor(l, 32);

    unsigned short* pO = partO + ((size_t)((b * 64 + nt) * 8 + qz)) * 4096;
    float*          pL = partL + ((size_t)((b * 64 + nt) * 8 + qz)) * 64;

    if (lane < 16) pL[w * 16 + lane] = l;   // lane == n here

#pragma unroll
    for (int ct = 0; ct < 4; ++ct)
#pragma unroll
        for (int r = 0; r < 4; ++r)
            pO[ct * 1024 + (quad * 4 + r) * 64 + w * 16 + n] = f2bf(acc[ct][r]);
}

// ---------------- merge 8 m-eighths + residual -------------------------------
// grid (256 n-tiles of 16, 2 b) = 512 blocks = 2 blocks/CU.
__global__ __launch_bounds__(256) void mergeq(
    const unsigned short* __restrict__ partO, const float* __restrict__ partL,
    const float* __restrict__ x, const float* __restrict__ gamma,
    float* __restrict__ out)
{
    int tid = threadIdx.x;
    int nt4 = blockIdx.x;       // 16-n tile index, 0..255
    int b   = blockIdx.y;
    int c   = tid >> 2;
    int j   = tid & 3;          // 4 n: j*4 .. j*4+3 within the 16-n tile
    int nt  = nt4 >> 2;         // 64-n attn tile
    int ns  = (nt4 & 3) * 16 + j * 4;   // offset within the 64-n tile

    const unsigned short* pOb = partO + ((size_t)((b * 64 + nt) * 8)) * 4096;
    const float*          pLb = partL + ((size_t)((b * 64 + nt) * 8)) * 64;
    float g = gamma[0];

    float4 o = {0.f, 0.f, 0.f, 0.f};
    float4 L = {0.f, 0.f, 0.f, 0.f};
#pragma unroll
    for (int qz = 0; qz < 8; ++qz) {
        ushort4 ov = *(const ushort4*)&pOb[qz * 4096 + c * 64 + ns];
        float4  lv = *(const float4*)&pLb[qz * 64 + ns];
        o.x += bf2f(ov.x); o.y += bf2f(ov.y);
        o.z += bf2f(ov.z); o.w += bf2f(ov.w);
        L.x += lv.x; L.y += lv.y; L.z += lv.z; L.w += lv.w;
    }
    size_t ob = ((size_t)b * 64 + c) * NTOK + (size_t)nt4 * 16 + j * 4;
    float4 xv = *(const float4*)&x[ob];
    float4 res;
    res.x = g * (o.x / L.x) + xv.x;
    res.y = g * (o.y / L.y) + xv.y;
    res.z = g * (o.z / L.z) + xv.z;
    res.w = g * (o.w / L.w) + xv.w;
    *(float4*)&out[ob] = res;
}

extern "C" void kernel_launch(void* const* d_in, const int* in_sizes, int n_in,
                              void* d_out, int out_size, void* d_ws, size_t ws_size,
                              hipStream_t stream) {
    const float* x     = (const float*)d_in[0];
    const float* ctx   = (const float*)d_in[1];
    const float* Wq    = (const float*)d_in[2];
    const float* bq    = (const float*)d_in[3];
    const float* Wk    = (const float*)d_in[4];
    const float* bk    = (const float*)d_in[5];
    const float* Wv    = (const float*)d_in[6];
    const float* bv    = (const float*)d_in[7];
    const float* gamma = (const float*)d_in[8];
    float* out = (float*)d_out;

    unsigned short* qbf   = (unsigned short*)d_ws;        // [2][4096][8]
    unsigned short* kbf   = qbf + 2 * NTOK * 8;           // [2][4096][8]
    unsigned short* vtp   = kbf + 2 * NTOK * 8;           // [2][128T][4ct][512] bf16
    unsigned short* partO = vtp + 2 * 64 * NTOK;          // [2*64*8][4096] bf16
    float*          partL = (float*)(partO + (size_t)2 * 64 * 8 * 4096); // [2*64*8][64]

    proj<<<dim3(64, 2, 5), 256, 0, stream>>>(x, ctx, Wq, bq, Wk, bk, Wv, bv, qbf, kbf, vtp);
    attn8<<<dim3(NTOK / 64, 2, 8), 256, 0, stream>>>(qbf, kbf, vtp, partO, partL);
    mergeq<<<dim3(NTOK / 16, 2), 256, 0, stream>>>(partO, partL, x, gamma, out);
}

// Round 5
// 95.642 us; speedup vs baseline: 1.1477x; 1.1477x over previous
//
#include <hip/hip_runtime.h>

#define NTOK 4096

typedef __attribute__((ext_vector_type(8))) short short8;
typedef __attribute__((ext_vector_type(4))) float f32x4;
typedef __attribute__((ext_vector_type(4))) unsigned int uint4v;

__device__ __forceinline__ unsigned short f2bf(float f) {
    unsigned u = __float_as_uint(f);
    u += 0x7fffu + ((u >> 16) & 1u);   // RNE; inputs finite
    return (unsigned short)(u >> 16);
}

__device__ __forceinline__ float bf2f(unsigned short h) {
    return __uint_as_float((unsigned)h << 16);
}

// pack two fp32 -> bf16 pair (truncation) in one v_perm_b32
__device__ __forceinline__ unsigned int pk2(float lo, float hi) {
    return __builtin_amdgcn_perm(__float_as_uint(hi), __float_as_uint(lo), 0x07060302u);
}

// pack two fp32 -> bf16 pair with RNE (matches f2bf stores)
__device__ __forceinline__ unsigned int pk2r(float lo, float hi) {
    return (unsigned)f2bf(lo) | ((unsigned)f2bf(hi) << 16);
}

// ---------------- projection ----------------
// grid (64 n-tiles, 2 b, 5 ogrp): ogrp0 = q(8)+k(8), ogrp1..4 = v channels 16 each
// outputs: qbf/kbf [b][n][8] bf16 (q pre-scaled by log2e),
// vtp TILE-CONTIGUOUS: per (32-m group T, ct) a 1 KB block in exact lane order:
//   short index = ((T*4 + ct)*64 + lane)*8 + j, lane = (ch&15) + 16*quad,
//   (quad, j) from the verified p-permutation p = quad*8+j of m within group.
// One attention A-fragment load = 64 lanes x 16 B = 1 KB contiguous burst.
__global__ __launch_bounds__(256) void proj(
    const float* __restrict__ x, const float* __restrict__ ctx,
    const float* __restrict__ Wq, const float* __restrict__ bq,
    const float* __restrict__ Wk, const float* __restrict__ bk,
    const float* __restrict__ Wv, const float* __restrict__ bv,
    unsigned short* __restrict__ qbf, unsigned short* __restrict__ kbf,
    unsigned short* __restrict__ vtp)
{
    __shared__ float sW[16 * 64];
    __shared__ float sB[16];
    int tid  = threadIdx.x;
    int ogrp = blockIdx.z;
    int b    = blockIdx.y;
    int n0   = blockIdx.x * 64;

    if (ogrp == 0) {
        for (int i = tid; i < 1024; i += 256)
            sW[i] = (i < 512) ? Wq[i] : Wk[i - 512];
        if (tid < 16) sB[tid] = (tid < 8) ? bq[tid] : bk[tid - 8];
    } else {
        for (int i = tid; i < 1024; i += 256)
            sW[i] = Wv[(ogrp - 1) * 1024 + i];
        if (tid < 16) sB[tid] = bv[(ogrp - 1) * 16 + tid];
    }
    __syncthreads();

    int nn   = tid & 63;
    int osub = tid >> 6;
    const float* inp = (ogrp == 0 && osub < 2) ? x : ctx;
    const float* ip  = inp + (size_t)b * 64 * NTOK + n0 + nn;

    float a0 = sB[osub * 4 + 0], a1 = sB[osub * 4 + 1];
    float a2 = sB[osub * 4 + 2], a3 = sB[osub * 4 + 3];
#pragma unroll 16
    for (int c = 0; c < 64; ++c) {
        float val = ip[(size_t)c * NTOK];
        a0 += sW[(osub * 4 + 0) * 64 + c] * val;
        a1 += sW[(osub * 4 + 1) * 64 + c] * val;
        a2 += sW[(osub * 4 + 2) * 64 + c] * val;
        a3 += sW[(osub * 4 + 3) * 64 + c] * val;
    }
    float av[4] = {a0, a1, a2, a3};

    if (ogrp == 0) {
        bool isq = osub < 2;
        float sc = isq ? 1.4426950408889634f : 1.0f;   // fold log2e into q
        unsigned short* dst = isq ? qbf : kbf;
        int half = osub & 1;
        ushort4 pk = {f2bf(av[0] * sc), f2bf(av[1] * sc), f2bf(av[2] * sc), f2bf(av[3] * sc)};
        *(ushort4*)&dst[((size_t)b * NTOK + n0 + nn) * 8 + half * 4] = pk;
    } else {                          // vtp bf16, tile-contiguous layout
        int cbase = (ogrp - 1) * 16 + osub * 4;
        int m   = n0 + nn;
        int T   = m >> 5;
        int mm  = m & 31;
        int p   = ((mm >> 2) & 3) * 8 + (mm >> 4) * 4 + (mm & 3);  // verified perm
        int qd  = p >> 3, j2 = p & 7;
        int ctv = cbase >> 4;          // constant across the 4 channels
        unsigned short* vB = vtp + (size_t)b * 64 * NTOK
                           + ((size_t)T * 4 + ctv) * 512;
#pragma unroll
        for (int jj = 0; jj < 4; ++jj) {
            int lanev = ((cbase + jj) & 15) + 16 * qd;
            vB[lanev * 8 + j2] = f2bf(av[jj]);
        }
    }
}

// ---------------- fused flash attention: V-reuse x4, 16 waves/CU, burst V ----
// block: (64-row n-tile nt, b, m-eighth qz), 256 thr = 4 waves.
// qz=8: 1024 blocks; VGPR=128 -> 4 blocks/CU resident = 16 waves/CU.
// m-SPLIT across waves (R4's n-split regressed: 4x K/V load redundancy +
// lost g-ILP cost more than the LDS epilogue saved — keep m-split).
// wave w owns m in [qz*512 + w*128, +128), 2 halves of 64 m.
// Per half: kf (4) + af (8, V frags) loaded ONCE, af reused across 4 n-groups.
// V loads are 1 KB contiguous bursts (tile layout above).
// Per-group machinery verbatim from verified attn5/6/7: S via mfma_16x16x32_bf16
// (K slots 8..31 zero, exec-masked quad-0 loads); S D-regs feed PV B-frags
// under the p-permutation; native v_exp2 (q carries log2e); no max-subtraction
// (energies bounded). Partial O bf16 + L fp32 to ws; mergeq finishes.
// R5: epilogue reduce in 2 super-chunks of 32 channels (35.8 KB LDS, still
// 4 blocks/CU: 143 <= 160 KB/CU) instead of 4 chunks: barriers 7 -> 3, and
// bf16 stores packed 2-per-dword (half the store instructions). Same bytes,
// same per-element arithmetic (RNE, 4-wave fp32 sum) as the verified path.
__global__ __launch_bounds__(256, 2) void attn8(
    const unsigned short* __restrict__ qbf, const unsigned short* __restrict__ kbf,
    const unsigned short* __restrict__ vtp,
    unsigned short* __restrict__ partO, float* __restrict__ partL)
{
    __shared__ float sOc[4][32][68];  // super-chunk: [wave][c-sub 32][n 64]
    __shared__ float sL[4][64];

    int tid  = threadIdx.x;
    int w    = tid >> 6, lane = tid & 63;
    int n    = lane & 15, quad = lane >> 4;
    int nt   = blockIdx.x;
    int b    = blockIdx.y;
    int qz   = blockIdx.z;           // 0..7
    int n0   = nt * 64;

    const f32x4 z4 = {0.f, 0.f, 0.f, 0.f};
    const short8 z8 = {0, 0, 0, 0, 0, 0, 0, 0};

    short8 bq[4];
#pragma unroll
    for (int g = 0; g < 4; ++g)
        bq[g] = (quad == 0)
            ? *(const short8*)&qbf[((size_t)b * NTOK + n0 + g * 16 + n) * 8]
            : z8;

    const unsigned short* kb = kbf + (size_t)b * NTOK * 8;
    const unsigned short* vb = vtp + (size_t)b * 64 * NTOK;
    int mwbase = qz * 512 + w * 128;

    f32x4 acc[4][4];
#pragma unroll
    for (int g = 0; g < 4; ++g)
#pragma unroll
        for (int ct = 0; ct < 4; ++ct) acc[g][ct] = z4;
    float lsum[4] = {0.f, 0.f, 0.f, 0.f};

    for (int h = 0; h < 2; ++h) {
        int m0 = mwbase + h * 64;
        int Tb = m0 >> 5;             // two 32-m groups: Tb, Tb+1

        short8 kf0 = (quad == 0) ? *(const short8*)&kb[(size_t)(m0 + 0 * 16 + n) * 8] : z8;
        short8 kf1 = (quad == 0) ? *(const short8*)&kb[(size_t)(m0 + 1 * 16 + n) * 8] : z8;
        short8 kf2 = (quad == 0) ? *(const short8*)&kb[(size_t)(m0 + 2 * 16 + n) * 8] : z8;
        short8 kf3 = (quad == 0) ? *(const short8*)&kb[(size_t)(m0 + 3 * 16 + n) * 8] : z8;

        // V fragments: 1 KB contiguous per load (lane-indexed tile)
        short8 af[2][4];
#pragma unroll
        for (int s = 0; s < 2; ++s)
#pragma unroll
            for (int ct = 0; ct < 4; ++ct)
                af[s][ct] = *(const short8*)&vb[(((size_t)(Tb + s) * 4 + ct) * 64 + lane) * 8];

#pragma unroll
        for (int g = 0; g < 4; ++g) {
            f32x4 sa0 = __builtin_amdgcn_mfma_f32_16x16x32_bf16(kf0, bq[g], z4, 0, 0, 0);
            f32x4 sa1 = __builtin_amdgcn_mfma_f32_16x16x32_bf16(kf1, bq[g], z4, 0, 0, 0);
            f32x4 sa2 = __builtin_amdgcn_mfma_f32_16x16x32_bf16(kf2, bq[g], z4, 0, 0, 0);
            f32x4 sa3 = __builtin_amdgcn_mfma_f32_16x16x32_bf16(kf3, bq[g], z4, 0, 0, 0);

            float e00 = __builtin_amdgcn_exp2f(sa0[0]), e01 = __builtin_amdgcn_exp2f(sa0[1]);
            float e02 = __builtin_amdgcn_exp2f(sa0[2]), e03 = __builtin_amdgcn_exp2f(sa0[3]);
            float e10 = __builtin_amdgcn_exp2f(sa1[0]), e11 = __builtin_amdgcn_exp2f(sa1[1]);
            float e12 = __builtin_amdgcn_exp2f(sa1[2]), e13 = __builtin_amdgcn_exp2f(sa1[3]);
            float e20 = __builtin_amdgcn_exp2f(sa2[0]), e21 = __builtin_amdgcn_exp2f(sa2[1]);
            float e22 = __builtin_amdgcn_exp2f(sa2[2]), e23 = __builtin_amdgcn_exp2f(sa2[3]);
            float e30 = __builtin_amdgcn_exp2f(sa3[0]), e31 = __builtin_amdgcn_exp2f(sa3[1]);
            float e32 = __builtin_amdgcn_exp2f(sa3[2]), e33 = __builtin_amdgcn_exp2f(sa3[3]);
            lsum[g] += ((e00 + e01) + (e02 + e03)) + ((e10 + e11) + (e12 + e13))
                     + ((e20 + e21) + (e22 + e23)) + ((e30 + e31) + (e32 + e33));

            uint4v t0, t1;
            t0[0] = pk2(e00, e01); t0[1] = pk2(e02, e03);
            t0[2] = pk2(e10, e11); t0[3] = pk2(e12, e13);
            t1[0] = pk2(e20, e21); t1[1] = pk2(e22, e23);
            t1[2] = pk2(e30, e31); t1[3] = pk2(e32, e33);
            short8 pf0 = __builtin_bit_cast(short8, t0);
            short8 pf1 = __builtin_bit_cast(short8, t1);

            acc[g][0] = __builtin_amdgcn_mfma_f32_16x16x32_bf16(af[0][0], pf0, acc[g][0], 0, 0, 0);
            acc[g][1] = __builtin_amdgcn_mfma_f32_16x16x32_bf16(af[0][1], pf0, acc[g][1], 0, 0, 0);
            acc[g][2] = __builtin_amdgcn_mfma_f32_16x16x32_bf16(af[0][2], pf0, acc[g][2], 0, 0, 0);
            acc[g][3] = __builtin_amdgcn_mfma_f32_16x16x32_bf16(af[0][3], pf0, acc[g][3], 0, 0, 0);
            acc[g][0] = __builtin_amdgcn_mfma_f32_16x16x32_bf16(af[1][0], pf1, acc[g][0], 0, 0, 0);
            acc[g][1] = __builtin_amdgcn_mfma_f32_16x16x32_bf16(af[1][1], pf1, acc[g][1], 0, 0, 0);
            acc[g][2] = __builtin_amdgcn_mfma_f32_16x16x32_bf16(af[1][2], pf1, acc[g][2], 0, 0, 0);
            acc[g][3] = __builtin_amdgcn_mfma_f32_16x16x32_bf16(af[1][3], pf1, acc[g][3], 0, 0, 0);
        }
    }

    // ---- epilogue: softmax denominators
#pragma unroll
    for (int g = 0; g < 4; ++g) {
        float l = lsum[g];
        l += __shfl_xor(l, 16);
        l += __shfl_xor(l, 32);
        if (lane < 16) sL[w][g * 16 + n] = l;
    }

    unsigned short* pO = partO + ((size_t)((b * 64 + nt) * 8 + qz)) * 4096;
    float*          pL = partL + ((size_t)((b * 64 + nt) * 8 + qz)) * 64;

    // ---- cross-wave reduce in 2 super-chunks (36 KB LDS, 3 barriers)
#pragma unroll
    for (int c2 = 0; c2 < 2; ++c2) {
        if (c2) __syncthreads();
#pragma unroll
        for (int g = 0; g < 4; ++g)
#pragma unroll
            for (int ctl = 0; ctl < 2; ++ctl)
#pragma unroll
                for (int r = 0; r < 4; ++r)
                    sOc[w][ctl * 16 + quad * 4 + r][g * 16 + n] = acc[g][c2 * 2 + ctl][r];
        __syncthreads();
        for (int i = tid; i < 1024; i += 256) {      // 1024 bf16-pairs / super-chunk
            int c16 = i >> 5, nn2 = (i & 31) * 2;
            float s0 = sOc[0][c16][nn2]     + sOc[1][c16][nn2]
                     + sOc[2][c16][nn2]     + sOc[3][c16][nn2];
            float s1 = sOc[0][c16][nn2 + 1] + sOc[1][c16][nn2 + 1]
                     + sOc[2][c16][nn2 + 1] + sOc[3][c16][nn2 + 1];
            *(unsigned*)&pO[c2 * 2048 + c16 * 64 + nn2] = pk2r(s0, s1);
        }
    }
    if (tid < 64)
        pL[tid] = sL[0][tid] + sL[1][tid] + sL[2][tid] + sL[3][tid];
}

// ---------------- merge 8 m-eighths + residual -------------------------------
// grid (256 n-tiles of 16, 2 b) = 512 blocks = 2 blocks/CU.
__global__ __launch_bounds__(256) void mergeq(
    const unsigned short* __restrict__ partO, const float* __restrict__ partL,
    const float* __restrict__ x, const float* __restrict__ gamma,
    float* __restrict__ out)
{
    int tid = threadIdx.x;
    int nt4 = blockIdx.x;       // 16-n tile index, 0..255
    int b   = blockIdx.y;
    int c   = tid >> 2;
    int j   = tid & 3;          // 4 n: j*4 .. j*4+3 within the 16-n tile
    int nt  = nt4 >> 2;         // 64-n attn tile
    int ns  = (nt4 & 3) * 16 + j * 4;   // offset within the 64-n tile

    const unsigned short* pOb = partO + ((size_t)((b * 64 + nt) * 8)) * 4096;
    const float*          pLb = partL + ((size_t)((b * 64 + nt) * 8)) * 64;
    float g = gamma[0];

    float4 o = {0.f, 0.f, 0.f, 0.f};
    float4 L = {0.f, 0.f, 0.f, 0.f};
#pragma unroll
    for (int qz = 0; qz < 8; ++qz) {
        ushort4 ov = *(const ushort4*)&pOb[qz * 4096 + c * 64 + ns];
        float4  lv = *(const float4*)&pLb[qz * 64 + ns];
        o.x += bf2f(ov.x); o.y += bf2f(ov.y);
        o.z += bf2f(ov.z); o.w += bf2f(ov.w);
        L.x += lv.x; L.y += lv.y; L.z += lv.z; L.w += lv.w;
    }
    size_t ob = ((size_t)b * 64 + c) * NTOK + (size_t)nt4 * 16 + j * 4;
    float4 xv = *(const float4*)&x[ob];
    float4 res;
    res.x = g * (o.x / L.x) + xv.x;
    res.y = g * (o.y / L.y) + xv.y;
    res.z = g * (o.z / L.z) + xv.z;
    res.w = g * (o.w / L.w) + xv.w;
    *(float4*)&out[ob] = res;
}

extern "C" void kernel_launch(void* const* d_in, const int* in_sizes, int n_in,
                              void* d_out, int out_size, void* d_ws, size_t ws_size,
                              hipStream_t stream) {
    const float* x     = (const float*)d_in[0];
    const float* ctx   = (const float*)d_in[1];
    const float* Wq    = (const float*)d_in[2];
    const float* bq    = (const float*)d_in[3];
    const float* Wk    = (const float*)d_in[4];
    const float* bk    = (const float*)d_in[5];
    const float* Wv    = (const float*)d_in[6];
    const float* bv    = (const float*)d_in[7];
    const float* gamma = (const float*)d_in[8];
    float* out = (float*)d_out;

    unsigned short* qbf   = (unsigned short*)d_ws;        // [2][4096][8]
    unsigned short* kbf   = qbf + 2 * NTOK * 8;           // [2][4096][8]
    unsigned short* vtp   = kbf + 2 * NTOK * 8;           // [2][128T][4ct][512] bf16
    unsigned short* partO = vtp + 2 * 64 * NTOK;          // [2*64*8][4096] bf16
    float*          partL = (float*)(partO + (size_t)2 * 64 * 8 * 4096); // [2*64*8][64]

    proj<<<dim3(64, 2, 5), 256, 0, stream>>>(x, ctx, Wq, bq, Wk, bk, Wv, bv, qbf, kbf, vtp);
    attn8<<<dim3(NTOK / 64, 2, 8), 256, 0, stream>>>(qbf, kbf, vtp, partO, partL);
    mergeq<<<dim3(NTOK / 16, 2), 256, 0, stream>>>(partO, partL, x, gamma, out);
}